// Round 10
// baseline (246.401 us; speedup 1.0000x reference)
//
#include <hip/hip_runtime.h>
#include <math.h>

#define DEG_EPS 1e-12f
#define LN_EPS  1e-5f

typedef __attribute__((ext_vector_type(8))) short bf16x8;
typedef __attribute__((ext_vector_type(4))) float f32x4;
typedef unsigned long long ull;

__device__ __forceinline__ short f2bf(float f) {      // fp32 -> bf16 RNE
    unsigned u = __float_as_uint(f);
    u += 0x7FFF + ((u >> 16) & 1);
    return (short)(u >> 16);
}
__device__ __forceinline__ float bf_lo(unsigned u) { return __uint_as_float(u << 16); }
__device__ __forceinline__ float bf_hi(unsigned u) { return __uint_as_float(u & 0xFFFF0000u); }

// ---------------------------------------------------------------------------
// ws layout (zeroed prefix first — one hipMemsetAsync covers it):
//   packed : N * 8       (bits [55:40] = edge count, bits [39:0] = sum(ew)*2^24)
//   status : 128 * 8     (decoupled-lookback {flag,val}; flag in bits 63:62)
//   vbc    : 8           (ticket counter)
//   ---- end of zeroed region ----
//   meta   : E * 8       (int2 {col, bitcast(ew*dis_c)})
//   xwb    : N * 64 * 2  (bf16 xw = x @ W^T)
//   ord    : E * 4       (within-row ordinal of each edge)
//   dis    : N * 4       (rsqrt(deg+eps))
//   rowptr : (N+1)*4
// ---------------------------------------------------------------------------

// count+deg atomics (blocks [0,cntB)) ∥ xw = x@W^T via MFMA (rest).
// The atomic pass leaves VALU/MFMA idle — xw rides under it for free.
__global__ __launch_bounds__(256) void k_count_xw(
    const int* __restrict__ rows, const float* __restrict__ ew,
    ull* __restrict__ packed, unsigned* __restrict__ ord,
    const float* __restrict__ x, const float* __restrict__ W,
    unsigned short* __restrict__ xwb,
    int E, int N, int Ntiles, int cntB)
{
    const int tid = threadIdx.x;
    if ((int)blockIdx.x < cntB) {
        for (int e = blockIdx.x * 256 + tid; e < E; e += cntB * 256) {
            int r = rows[e];
            ull fx = (ull)__float2uint_rn(ew[e] * 16777216.0f);
            ull old = atomicAdd(&packed[r], (1ULL << 40) | fx);
            ord[e] = (unsigned)(old >> 40);
        }
    } else {
        const int lane = tid & 63;
        const int m = lane & 15;
        const int q = lane >> 4;
        const int xwB = gridDim.x - cntB;
        const int wave = (blockIdx.x - cntB) * 4 + (tid >> 6);
        const int nwv = xwB * 4;

        bf16x8 bfrag[4][2];                      // W fragments, loaded once
#pragma unroll
        for (int f = 0; f < 4; ++f)
#pragma unroll
            for (int s = 0; s < 2; ++s) {
                const float4* wp = (const float4*)(W + (f * 16 + m) * 64 + s * 32 + q * 8);
                float4 lo = wp[0], hi = wp[1];
                bf16x8 v;
                v[0] = f2bf(lo.x); v[1] = f2bf(lo.y); v[2] = f2bf(lo.z); v[3] = f2bf(lo.w);
                v[4] = f2bf(hi.x); v[5] = f2bf(hi.y); v[6] = f2bf(hi.z); v[7] = f2bf(hi.w);
                bfrag[f][s] = v;
            }

        for (int t = wave; t < Ntiles; t += nwv) {
            int n0 = t * 16;
            int nr = n0 + m; if (nr >= N) nr = N - 1;
            bf16x8 afrag[2];
#pragma unroll
            for (int s = 0; s < 2; ++s) {
                const float4* xp = (const float4*)(x + (size_t)nr * 64 + s * 32 + q * 8);
                float4 lo = xp[0], hi = xp[1];
                bf16x8 v;
                v[0] = f2bf(lo.x); v[1] = f2bf(lo.y); v[2] = f2bf(lo.z); v[3] = f2bf(lo.w);
                v[4] = f2bf(hi.x); v[5] = f2bf(hi.y); v[6] = f2bf(hi.z); v[7] = f2bf(hi.w);
                afrag[s] = v;
            }
#pragma unroll
            for (int f = 0; f < 4; ++f) {
                f32x4 acc = {0.f, 0.f, 0.f, 0.f};
                acc = __builtin_amdgcn_mfma_f32_16x16x32_bf16(afrag[0], bfrag[f][0], acc, 0, 0, 0);
                acc = __builtin_amdgcn_mfma_f32_16x16x32_bf16(afrag[1], bfrag[f][1], acc, 0, 0, 0);
#pragma unroll
                for (int r4 = 0; r4 < 4; ++r4) {
                    int node = n0 + q * 4 + r4;
                    if (node < N)
                        xwb[(size_t)node * 64 + f * 16 + m] = (unsigned short)f2bf(acc[r4]);
                }
            }
        }
    }
}

// ---------------------------------------------------------------------------
// Single-kernel decoupled-lookback scan: counts -> rowptr (exclusive) + dis.
// Ordered virtual block id via atomic ticket; status[vb] = {flag:2,val:32},
// flag 1 = aggregate available, 2 = inclusive prefix available.
// 98 blocks, all co-resident -> lookback cannot deadlock.
// ---------------------------------------------------------------------------
__global__ __launch_bounds__(256) void k_scan_lb(
    const ull* __restrict__ packed, ull* __restrict__ status,
    int* __restrict__ vbc, int* __restrict__ rowptr,
    float* __restrict__ dis, int N, int NB)
{
    __shared__ int sc[256];
    __shared__ int sh_vb, sh_excl;
    const int t = threadIdx.x;
    if (t == 0) sh_vb = atomicAdd(vbc, 1);
    __syncthreads();
    const int vb = sh_vb;

    int base = vb * 1024 + t * 4;
    int c[4]; int s = 0;
#pragma unroll
    for (int k = 0; k < 4; ++k) {
        int i = base + k;
        ull p = (i < N) ? packed[i] : 0ULL;
        c[k] = (int)(p >> 40);
        s += c[k];
        if (i < N) {
            double deg = 1.0 + (double)(p & 0xFFFFFFFFFFULL) * (1.0 / 16777216.0);
            dis[i] = rsqrtf((float)deg + DEG_EPS);
        }
    }
    sc[t] = s; __syncthreads();
    int my = s;
    for (int off = 1; off < 256; off <<= 1) {
        int u = (t >= off) ? sc[t - off] : 0;
        __syncthreads();
        sc[t] += u;
        __syncthreads();
    }
    const int T = sc[255];

    if (t == 0) {
        if (vb == 0) {
            __hip_atomic_store(&status[0], (2ULL << 62) | (unsigned)T,
                               __ATOMIC_RELEASE, __HIP_MEMORY_SCOPE_AGENT);
            sh_excl = 0;
        } else {
            __hip_atomic_store(&status[vb], (1ULL << 62) | (unsigned)T,
                               __ATOMIC_RELEASE, __HIP_MEMORY_SCOPE_AGENT);
            int excl = 0;
            for (int j = vb - 1; j >= 0; --j) {
                ull v;
                do {
                    v = __hip_atomic_load(&status[j], __ATOMIC_ACQUIRE,
                                          __HIP_MEMORY_SCOPE_AGENT);
                    if ((v >> 62) == 0) __builtin_amdgcn_s_sleep(1);
                } while ((v >> 62) == 0);
                excl += (int)(v & 0xFFFFFFFFULL);
                if ((v >> 62) == 2ULL) break;
            }
            __hip_atomic_store(&status[vb], (2ULL << 62) | (unsigned)(excl + T),
                               __ATOMIC_RELEASE, __HIP_MEMORY_SCOPE_AGENT);
            sh_excl = excl;
        }
    }
    __syncthreads();

    int run = sh_excl + sc[t] - my;
#pragma unroll
    for (int k = 0; k < 4; ++k) {
        int i = base + k;
        if (i < N) rowptr[i] = run;
        run += c[k];
    }
    if (vb == NB - 1 && t == 0) rowptr[N] = sh_excl + T;   // == E
}

// fill CSR — atomic-free: slot = rowptr[r] + ord[e]; meta = {col, ew*dis_c}
// (dis_r factored out of the row sum — applied wave-uniformly in spmm)
__global__ __launch_bounds__(256) void k_fill(const int* __restrict__ rows,
                                              const int* __restrict__ cols,
                                              const float* __restrict__ ew,
                                              const unsigned* __restrict__ ord,
                                              const float* __restrict__ dis,
                                              const int* __restrict__ rowptr,
                                              int2* __restrict__ meta, int E) {
    int e = blockIdx.x * blockDim.x + threadIdx.x;
    if (e < E) {
        int r = rows[e], c = cols[e];
        float nw = ew[e] * dis[c];
        meta[rowptr[r] + (int)ord[e]] = make_int2(c, __float_as_int(nw));
    }
}

// ---------------------------------------------------------------------------
// Fused SpMM + bias + GELU + LayerNorm + residual.  One wave per row.
//   16 lanes per edge, 4 features per lane (uint2 = 4 bf16).
//   z = dis_r * ( sum_e (ew*dis_c)*xw_c  +  dis_r*xw_row )
// ---------------------------------------------------------------------------
__global__ __launch_bounds__(256) void k_spmm_fused(
    const int* __restrict__ rowptr, const int2* __restrict__ meta,
    const float* __restrict__ dis, const uint2* __restrict__ xw4,
    const float* __restrict__ x, const float* __restrict__ bias,
    const float* __restrict__ gamma, const float* __restrict__ beta,
    float* __restrict__ out, int N)
{
    int t = blockIdx.x * blockDim.x + threadIdx.x;
    int row = t >> 6;
    if (row >= N) return;
    const int lane = t & 63;
    const int k  = lane & 15;   // feature quad: features 4k..4k+3
    const int qh = lane >> 4;   // edge quarter 0..3

    const float disr = dis[row];   // wave-uniform

    float a0 = 0.f, a1 = 0.f, a2 = 0.f, a3 = 0.f;
    if (qh == 0) {              // self loop term: dis_r*xw_row (z gets *dis_r later)
        uint2 v = xw4[(size_t)row * 16 + k];
        a0 = bf_lo(v.x) * disr; a1 = bf_hi(v.x) * disr;
        a2 = bf_lo(v.y) * disr; a3 = bf_hi(v.y) * disr;
    }

    int start = rowptr[row], end = rowptr[row + 1];
    for (int base = start; base < end; base += 64) {
        int rem = end - base;
        int cnt = rem < 64 ? rem : 64;
        int2 m = make_int2(0, 0);
        if (lane < cnt) m = meta[base + lane];   // 64 edges, one coalesced load
        int tmax = (cnt + 3) >> 2;               // 4 edges per step
        int tt = 0;
        for (; tt + 2 <= tmax; tt += 2) {        // 8 edges in flight
            int j0 = 4 * tt + qh, j1 = 4 * (tt + 1) + qh;
            int   c0 = __shfl(m.x, j0, 64);
            float w0 = __int_as_float(__shfl(m.y, j0, 64));
            int   c1 = __shfl(m.x, j1, 64);
            float w1 = __int_as_float(__shfl(m.y, j1, 64));
            if (j0 >= cnt) { w0 = 0.f; c0 = 0; }
            if (j1 >= cnt) { w1 = 0.f; c1 = 0; }
            uint2 v0 = xw4[(size_t)c0 * 16 + k];
            uint2 v1 = xw4[(size_t)c1 * 16 + k];
            a0 = fmaf(bf_lo(v0.x), w0, a0); a1 = fmaf(bf_hi(v0.x), w0, a1);
            a2 = fmaf(bf_lo(v0.y), w0, a2); a3 = fmaf(bf_hi(v0.y), w0, a3);
            a0 = fmaf(bf_lo(v1.x), w1, a0); a1 = fmaf(bf_hi(v1.x), w1, a1);
            a2 = fmaf(bf_lo(v1.y), w1, a2); a3 = fmaf(bf_hi(v1.y), w1, a3);
        }
        for (; tt < tmax; ++tt) {
            int j = 4 * tt + qh;
            int   c = __shfl(m.x, j, 64);
            float w = __int_as_float(__shfl(m.y, j, 64));
            if (j >= cnt) { w = 0.f; c = 0; }
            uint2 v = xw4[(size_t)c * 16 + k];
            a0 = fmaf(bf_lo(v.x), w, a0); a1 = fmaf(bf_hi(v.x), w, a1);
            a2 = fmaf(bf_lo(v.y), w, a2); a3 = fmaf(bf_hi(v.y), w, a3);
        }
    }

    // combine the 4 edge-quarters (lanes k, k+16, k+32, k+48)
#pragma unroll
    for (int mk = 16; mk < 64; mk <<= 1) {
        a0 += __shfl_xor(a0, mk, 64);
        a1 += __shfl_xor(a1, mk, 64);
        a2 += __shfl_xor(a2, mk, 64);
        a3 += __shfl_xor(a3, mk, 64);
    }

    // lane finishes feature f = 4k + qh
    float a = (qh == 0) ? a0 : (qh == 1) ? a1 : (qh == 2) ? a2 : a3;
    int f = 4 * k + qh;
    a = a * disr + bias[f];
    a = 0.5f * a * (1.0f + erff(a * 0.70710678118654752f));   // exact gelu

    float sum = a, ssq = a * a;
#pragma unroll
    for (int mk = 1; mk < 64; mk <<= 1) {
        sum += __shfl_xor(sum, mk, 64);
        ssq += __shfl_xor(ssq, mk, 64);
    }
    float mean = sum * (1.0f / 64.0f);
    float var  = fmaxf(ssq * (1.0f / 64.0f) - mean * mean, 0.0f);
    float rs   = rsqrtf(var + LN_EPS);
    float nrm  = (a - mean) * rs;

    // transpose so feature == lane, then coalesced store
    float nv = __shfl(nrm, ((lane & 3) << 4) | (lane >> 2), 64);
    out[(size_t)row * 64 + lane] =
        nv * gamma[lane] + beta[lane] + x[(size_t)row * 64 + lane];
}

// ---------------------------------------------------------------------------
extern "C" void kernel_launch(void* const* d_in, const int* in_sizes, int n_in,
                              void* d_out, int out_size, void* d_ws, size_t ws_size,
                              hipStream_t stream) {
    const float* x   = (const float*)d_in[0];
    const int*   ei  = (const int*)  d_in[1];   // [2,E] flat: rows then cols
    const float* ew  = (const float*)d_in[2];
    const float* W   = (const float*)d_in[3];
    const float* b   = (const float*)d_in[4];
    const float* g   = (const float*)d_in[5];
    const float* bt  = (const float*)d_in[6];
    float* out = (float*)d_out;

    const int N = in_sizes[0] / 64;
    const int E = in_sizes[1] / 2;
    const int* rows = ei;
    const int* cols = ei + E;
    const int NB = (N + 1023) / 1024;
    const int Ntiles = (N + 15) / 16;

    // ws carve-up (zeroed prefix first)
    char* w8 = (char*)d_ws;
    ull*   packed = (ull*)w8;                 w8 += (size_t)N * 8;
    ull*   status = (ull*)w8;                 w8 += 128 * 8;
    int*   vbc    = (int*)w8;                 w8 += 8;
    const size_t zero_bytes = (size_t)N * 8 + 128 * 8 + 8;
    int2*           meta = (int2*)w8;         w8 += (size_t)E * 8;
    unsigned short* xwb  = (unsigned short*)w8; w8 += (size_t)N * 128;
    unsigned*       ord  = (unsigned*)w8;     w8 += (size_t)E * 4;
    float*          dis  = (float*)w8;        w8 += (size_t)N * 4;
    int*          rowptr = (int*)w8;

    hipMemsetAsync(packed, 0, zero_bytes, stream);

    const int cntB = 1792, xwB = 256;
    k_count_xw<<<cntB + xwB, 256, 0, stream>>>(rows, ew, packed, ord,
                                               x, W, xwb, E, N, Ntiles, cntB);

    k_scan_lb<<<NB, 256, 0, stream>>>(packed, status, vbc, rowptr, dis, N, NB);

    k_fill<<<(E + 255) / 256, 256, 0, stream>>>(rows, cols, ew, ord, dis,
                                                rowptr, meta, E);

    long total = (long)N * 64;
    k_spmm_fused<<<(int)((total + 255) / 256), 256, 0, stream>>>(
        rowptr, meta, dis, (const uint2*)xwb, x, b, g, bt, out, N);
}

// Round 11
// 237.346 us; speedup vs baseline: 1.0382x; 1.0382x over previous
//
#include <hip/hip_runtime.h>
#include <math.h>

#define DEG_EPS 1e-12f
#define LN_EPS  1e-5f

typedef __attribute__((ext_vector_type(8))) short bf16x8;
typedef __attribute__((ext_vector_type(4))) float f32x4;
typedef unsigned long long ull;

__device__ __forceinline__ short f2bf(float f) {      // fp32 -> bf16 RNE
    unsigned u = __float_as_uint(f);
    u += 0x7FFF + ((u >> 16) & 1);
    return (short)(u >> 16);
}
__device__ __forceinline__ float bf_lo(unsigned u) { return __uint_as_float(u << 16); }
__device__ __forceinline__ float bf_hi(unsigned u) { return __uint_as_float(u & 0xFFFF0000u); }

// ---------------------------------------------------------------------------
// ws layout (zeroed prefix first — one hipMemsetAsync covers it):
//   packed : N * 8       (bits [55:40] = edge count, bits [39:0] = sum(ew)*2^24)
//   status : 128 * 8     (decoupled-lookback {flag,val}; flag in bits 63:62)
//   vbc    : 8           (ticket counter)
//   ---- end of zeroed region ----
//   meta   : E * 8       (int2 {col, bitcast(ew*dis_c)})
//   xwb    : N * 64 * 2  (bf16 xw = x @ W^T)
//   ord    : E * 4       (within-row ordinal of each edge)
//   dis    : N * 4       (rsqrt(deg+eps))
//   rowptr : (N+1)*4
// ---------------------------------------------------------------------------

// one 64-bit atomic per edge (1 edge/thread, max outstanding);
// atomic return gives the within-row ordinal for free
__global__ __launch_bounds__(256) void k_count_deg(const int* __restrict__ rows,
                                                   const float* __restrict__ ew,
                                                   ull* __restrict__ packed,
                                                   unsigned* __restrict__ ord, int E) {
    int e = blockIdx.x * blockDim.x + threadIdx.x;
    if (e < E) {
        int r = rows[e];
        ull fx = (ull)__float2uint_rn(ew[e] * 16777216.0f);
        ull old = atomicAdd(&packed[r], (1ULL << 40) | fx);
        ord[e] = (unsigned)(old >> 40);
    }
}

// ---------------------------------------------------------------------------
// Single-kernel decoupled-lookback scan: counts -> rowptr (exclusive) + dis.
// Ordered virtual block id via atomic ticket; status[vb] = {flag:2,val:32},
// flag 1 = aggregate available, 2 = inclusive prefix available.
// NB (~98) blocks, all co-resident -> lookback cannot deadlock.
// ---------------------------------------------------------------------------
__global__ __launch_bounds__(256) void k_scan_lb(
    const ull* __restrict__ packed, ull* __restrict__ status,
    int* __restrict__ vbc, int* __restrict__ rowptr,
    float* __restrict__ dis, int N, int NB)
{
    __shared__ int sc[256];
    __shared__ int sh_vb, sh_excl;
    const int t = threadIdx.x;
    if (t == 0) sh_vb = atomicAdd(vbc, 1);
    __syncthreads();
    const int vb = sh_vb;

    int base = vb * 1024 + t * 4;
    int c[4]; int s = 0;
#pragma unroll
    for (int k = 0; k < 4; ++k) {
        int i = base + k;
        ull p = (i < N) ? packed[i] : 0ULL;
        c[k] = (int)(p >> 40);
        s += c[k];
        if (i < N) {
            double deg = 1.0 + (double)(p & 0xFFFFFFFFFFULL) * (1.0 / 16777216.0);
            dis[i] = rsqrtf((float)deg + DEG_EPS);
        }
    }
    sc[t] = s; __syncthreads();
    int my = s;
    for (int off = 1; off < 256; off <<= 1) {
        int u = (t >= off) ? sc[t - off] : 0;
        __syncthreads();
        sc[t] += u;
        __syncthreads();
    }
    const int T = sc[255];

    if (t == 0) {
        if (vb == 0) {
            __hip_atomic_store(&status[0], (2ULL << 62) | (unsigned)T,
                               __ATOMIC_RELEASE, __HIP_MEMORY_SCOPE_AGENT);
            sh_excl = 0;
        } else {
            __hip_atomic_store(&status[vb], (1ULL << 62) | (unsigned)T,
                               __ATOMIC_RELEASE, __HIP_MEMORY_SCOPE_AGENT);
            int excl = 0;
            for (int j = vb - 1; j >= 0; --j) {
                ull v;
                do {
                    v = __hip_atomic_load(&status[j], __ATOMIC_ACQUIRE,
                                          __HIP_MEMORY_SCOPE_AGENT);
                    if ((v >> 62) == 0) __builtin_amdgcn_s_sleep(1);
                } while ((v >> 62) == 0);
                excl += (int)(v & 0xFFFFFFFFULL);
                if ((v >> 62) == 2ULL) break;
            }
            __hip_atomic_store(&status[vb], (2ULL << 62) | (unsigned)(excl + T),
                               __ATOMIC_RELEASE, __HIP_MEMORY_SCOPE_AGENT);
            sh_excl = excl;
        }
    }
    __syncthreads();

    int run = sh_excl + sc[t] - my;
#pragma unroll
    for (int k = 0; k < 4; ++k) {
        int i = base + k;
        if (i < N) rowptr[i] = run;
        run += c[k];
    }
    if (vb == NB - 1 && t == 0) rowptr[N] = sh_excl + T;   // == E
}

// ---------------------------------------------------------------------------
// fill CSR (blocks [0,fillB)) ∥ xw = x@W^T via MFMA (blocks [fillB, grid))
//   meta = {col, ew*dis_c}  (dis_r factored out, applied in spmm)
// ---------------------------------------------------------------------------
__global__ __launch_bounds__(256) void k_fill_xw(
    const int* __restrict__ rows, const int* __restrict__ cols,
    const float* __restrict__ ew, const unsigned* __restrict__ ord,
    const float* __restrict__ dis, const int* __restrict__ rowptr,
    int2* __restrict__ meta,
    const float* __restrict__ x, const float* __restrict__ W,
    unsigned short* __restrict__ xwb,
    int E, int N, int Ntiles, int fillB)
{
    const int tid = threadIdx.x;
    if ((int)blockIdx.x < fillB) {
        for (int e = blockIdx.x * 256 + tid; e < E; e += fillB * 256) {
            int r = rows[e], c = cols[e];
            float nw = ew[e] * dis[c];
            meta[rowptr[r] + (int)ord[e]] = make_int2(c, __float_as_int(nw));
        }
    } else {
        const int lane = tid & 63;
        const int m = lane & 15;
        const int q = lane >> 4;
        const int xwB = gridDim.x - fillB;
        const int wave = (blockIdx.x - fillB) * 4 + (tid >> 6);
        const int nwv = xwB * 4;

        bf16x8 bfrag[4][2];                      // W fragments, loaded once
#pragma unroll
        for (int f = 0; f < 4; ++f)
#pragma unroll
            for (int s = 0; s < 2; ++s) {
                const float4* wp = (const float4*)(W + (f * 16 + m) * 64 + s * 32 + q * 8);
                float4 lo = wp[0], hi = wp[1];
                bf16x8 v;
                v[0] = f2bf(lo.x); v[1] = f2bf(lo.y); v[2] = f2bf(lo.z); v[3] = f2bf(lo.w);
                v[4] = f2bf(hi.x); v[5] = f2bf(hi.y); v[6] = f2bf(hi.z); v[7] = f2bf(hi.w);
                bfrag[f][s] = v;
            }

        for (int t = wave; t < Ntiles; t += nwv) {
            int n0 = t * 16;
            int nr = n0 + m; if (nr >= N) nr = N - 1;
            bf16x8 afrag[2];
#pragma unroll
            for (int s = 0; s < 2; ++s) {
                const float4* xp = (const float4*)(x + (size_t)nr * 64 + s * 32 + q * 8);
                float4 lo = xp[0], hi = xp[1];
                bf16x8 v;
                v[0] = f2bf(lo.x); v[1] = f2bf(lo.y); v[2] = f2bf(lo.z); v[3] = f2bf(lo.w);
                v[4] = f2bf(hi.x); v[5] = f2bf(hi.y); v[6] = f2bf(hi.z); v[7] = f2bf(hi.w);
                afrag[s] = v;
            }
#pragma unroll
            for (int f = 0; f < 4; ++f) {
                f32x4 acc = {0.f, 0.f, 0.f, 0.f};
                acc = __builtin_amdgcn_mfma_f32_16x16x32_bf16(afrag[0], bfrag[f][0], acc, 0, 0, 0);
                acc = __builtin_amdgcn_mfma_f32_16x16x32_bf16(afrag[1], bfrag[f][1], acc, 0, 0, 0);
#pragma unroll
                for (int r4 = 0; r4 < 4; ++r4) {
                    int node = n0 + q * 4 + r4;
                    if (node < N)
                        xwb[(size_t)node * 64 + f * 16 + m] = (unsigned short)f2bf(acc[r4]);
                }
            }
        }
    }
}

// ---------------------------------------------------------------------------
// Fused SpMM + bias + GELU + LayerNorm + residual.  One wave per row.
//   16 lanes per edge, 4 features per lane (uint2 = 4 bf16).
//   z = dis_r * ( sum_e (ew*dis_c)*xw_c  +  dis_r*xw_row )
// ---------------------------------------------------------------------------
__global__ __launch_bounds__(256) void k_spmm_fused(
    const int* __restrict__ rowptr, const int2* __restrict__ meta,
    const float* __restrict__ dis, const uint2* __restrict__ xw4,
    const float* __restrict__ x, const float* __restrict__ bias,
    const float* __restrict__ gamma, const float* __restrict__ beta,
    float* __restrict__ out, int N)
{
    int t = blockIdx.x * blockDim.x + threadIdx.x;
    int row = t >> 6;
    if (row >= N) return;
    const int lane = t & 63;
    const int k  = lane & 15;   // feature quad: features 4k..4k+3
    const int qh = lane >> 4;   // edge quarter 0..3

    const float disr = dis[row];   // wave-uniform

    float a0 = 0.f, a1 = 0.f, a2 = 0.f, a3 = 0.f;
    if (qh == 0) {              // self loop term: dis_r*xw_row (z gets *dis_r later)
        uint2 v = xw4[(size_t)row * 16 + k];
        a0 = bf_lo(v.x) * disr; a1 = bf_hi(v.x) * disr;
        a2 = bf_lo(v.y) * disr; a3 = bf_hi(v.y) * disr;
    }

    int start = rowptr[row], end = rowptr[row + 1];
    for (int base = start; base < end; base += 64) {
        int rem = end - base;
        int cnt = rem < 64 ? rem : 64;
        int2 m = make_int2(0, 0);
        if (lane < cnt) m = meta[base + lane];   // 64 edges, one coalesced load
        int tmax = (cnt + 3) >> 2;               // 4 edges per step
        int tt = 0;
        for (; tt + 2 <= tmax; tt += 2) {        // 8 edges in flight
            int j0 = 4 * tt + qh, j1 = 4 * (tt + 1) + qh;
            int   c0 = __shfl(m.x, j0, 64);
            float w0 = __int_as_float(__shfl(m.y, j0, 64));
            int   c1 = __shfl(m.x, j1, 64);
            float w1 = __int_as_float(__shfl(m.y, j1, 64));
            if (j0 >= cnt) { w0 = 0.f; c0 = 0; }
            if (j1 >= cnt) { w1 = 0.f; c1 = 0; }
            uint2 v0 = xw4[(size_t)c0 * 16 + k];
            uint2 v1 = xw4[(size_t)c1 * 16 + k];
            a0 = fmaf(bf_lo(v0.x), w0, a0); a1 = fmaf(bf_hi(v0.x), w0, a1);
            a2 = fmaf(bf_lo(v0.y), w0, a2); a3 = fmaf(bf_hi(v0.y), w0, a3);
            a0 = fmaf(bf_lo(v1.x), w1, a0); a1 = fmaf(bf_hi(v1.x), w1, a1);
            a2 = fmaf(bf_lo(v1.y), w1, a2); a3 = fmaf(bf_hi(v1.y), w1, a3);
        }
        for (; tt < tmax; ++tt) {
            int j = 4 * tt + qh;
            int   c = __shfl(m.x, j, 64);
            float w = __int_as_float(__shfl(m.y, j, 64));
            if (j >= cnt) { w = 0.f; c = 0; }
            uint2 v = xw4[(size_t)c * 16 + k];
            a0 = fmaf(bf_lo(v.x), w, a0); a1 = fmaf(bf_hi(v.x), w, a1);
            a2 = fmaf(bf_lo(v.y), w, a2); a3 = fmaf(bf_hi(v.y), w, a3);
        }
    }

    // combine the 4 edge-quarters (lanes k, k+16, k+32, k+48)
#pragma unroll
    for (int mk = 16; mk < 64; mk <<= 1) {
        a0 += __shfl_xor(a0, mk, 64);
        a1 += __shfl_xor(a1, mk, 64);
        a2 += __shfl_xor(a2, mk, 64);
        a3 += __shfl_xor(a3, mk, 64);
    }

    // lane finishes feature f = 4k + qh
    float a = (qh == 0) ? a0 : (qh == 1) ? a1 : (qh == 2) ? a2 : a3;
    int f = 4 * k + qh;
    a = a * disr + bias[f];
    a = 0.5f * a * (1.0f + erff(a * 0.70710678118654752f));   // exact gelu

    float sum = a, ssq = a * a;
#pragma unroll
    for (int mk = 1; mk < 64; mk <<= 1) {
        sum += __shfl_xor(sum, mk, 64);
        ssq += __shfl_xor(ssq, mk, 64);
    }
    float mean = sum * (1.0f / 64.0f);
    float var  = fmaxf(ssq * (1.0f / 64.0f) - mean * mean, 0.0f);
    float rs   = rsqrtf(var + LN_EPS);
    float nrm  = (a - mean) * rs;

    // transpose so feature == lane, then coalesced store
    float nv = __shfl(nrm, ((lane & 3) << 4) | (lane >> 2), 64);
    out[(size_t)row * 64 + lane] =
        nv * gamma[lane] + beta[lane] + x[(size_t)row * 64 + lane];
}

// ---------------------------------------------------------------------------
extern "C" void kernel_launch(void* const* d_in, const int* in_sizes, int n_in,
                              void* d_out, int out_size, void* d_ws, size_t ws_size,
                              hipStream_t stream) {
    const float* x   = (const float*)d_in[0];
    const int*   ei  = (const int*)  d_in[1];   // [2,E] flat: rows then cols
    const float* ew  = (const float*)d_in[2];
    const float* W   = (const float*)d_in[3];
    const float* b   = (const float*)d_in[4];
    const float* g   = (const float*)d_in[5];
    const float* bt  = (const float*)d_in[6];
    float* out = (float*)d_out;

    const int N = in_sizes[0] / 64;
    const int E = in_sizes[1] / 2;
    const int* rows = ei;
    const int* cols = ei + E;
    const int NB = (N + 1023) / 1024;
    const int Ntiles = (N + 15) / 16;

    // ws carve-up (zeroed prefix first)
    char* w8 = (char*)d_ws;
    ull*   packed = (ull*)w8;                   w8 += (size_t)N * 8;
    ull*   status = (ull*)w8;                   w8 += 128 * 8;
    int*   vbc    = (int*)w8;                   w8 += 8;
    const size_t zero_bytes = (size_t)N * 8 + 128 * 8 + 8;
    int2*           meta = (int2*)w8;           w8 += (size_t)E * 8;
    unsigned short* xwb  = (unsigned short*)w8; w8 += (size_t)N * 128;
    unsigned*       ord  = (unsigned*)w8;       w8 += (size_t)E * 4;
    float*          dis  = (float*)w8;          w8 += (size_t)N * 4;
    int*          rowptr = (int*)w8;

    hipMemsetAsync(packed, 0, zero_bytes, stream);

    k_count_deg<<<(E + 255) / 256, 256, 0, stream>>>(rows, ew, packed, ord, E);

    k_scan_lb<<<NB, 256, 0, stream>>>(packed, status, vbc, rowptr, dis, N, NB);

    const int fillB = 1024, xwB = 256;
    k_fill_xw<<<fillB + xwB, 256, 0, stream>>>(rows, cols, ew, ord, dis, rowptr,
                                               meta, x, W, xwb, E, N, Ntiles, fillB);

    long total = (long)N * 64;
    k_spmm_fused<<<(int)((total + 255) / 256), 256, 0, stream>>>(
        rowptr, meta, dis, (const uint2*)xwb, x, b, g, bt, out, N);
}